// Round 1
// baseline (25.602 us; speedup 1.0000x reference)
//
#include <hip/hip_runtime.h>

// Fused 4D max pool, K=2 S=2 P=0 over (T,D,H,W) of [B=2,C=16,T=32,D=32,H=32,W=32] f32.
// Output [2,16,16,16,16,16] f32.
//
// Each thread: 2 output elements along W (one float4 of input per (t,d,h) corner,
// 8 corners total), 16-way max, one float2 store. Reads input exactly once.

#define BC   32          // B*C
#define IT   32
#define ID   32
#define IH   32
#define IW   32          // floats; 8 float4 per row
#define OT   16
#define OD   16
#define OH   16
#define OW   16          // 8 float2 pairs per row

__global__ __launch_bounds__(256) void maxpool4d_kernel(
    const float4* __restrict__ x4, float2* __restrict__ out2)
{
    int idx = blockIdx.x * blockDim.x + threadIdx.x;
    // idx = ((((bc*OT + ot)*OD + od)*OH + oh)*8 + owp)
    int owp = idx & 7;
    int oh  = (idx >> 3)  & 15;
    int od  = (idx >> 7)  & 15;
    int ot  = (idx >> 11) & 15;
    int bc  = idx >> 15;

    int t0 = ot << 1, d0 = od << 1, h0 = oh << 1;

    // input float4 index: (((bc*IT + t)*ID + d)*IH + h)*8 + owp
    int base = ((bc * IT + t0) * ID + d0) * IH + h0;  // in rows (of 8 float4)

    float4 acc;
    bool first = true;
    #pragma unroll
    for (int tt = 0; tt < 2; ++tt) {
        #pragma unroll
        for (int dd = 0; dd < 2; ++dd) {
            #pragma unroll
            for (int hh = 0; hh < 2; ++hh) {
                int row = base + ((tt * ID + dd) * IH + hh);
                float4 v = x4[row * 8 + owp];
                if (first) {
                    acc = v; first = false;
                } else {
                    acc.x = fmaxf(acc.x, v.x);
                    acc.y = fmaxf(acc.y, v.y);
                    acc.z = fmaxf(acc.z, v.z);
                    acc.w = fmaxf(acc.w, v.w);
                }
            }
        }
    }

    float2 r;
    r.x = fmaxf(acc.x, acc.y);
    r.y = fmaxf(acc.z, acc.w);
    out2[idx] = r;
}

extern "C" void kernel_launch(void* const* d_in, const int* in_sizes, int n_in,
                              void* d_out, int out_size, void* d_ws, size_t ws_size,
                              hipStream_t stream)
{
    const float4* x4 = (const float4*)d_in[0];
    float2* out2 = (float2*)d_out;

    int n_pairs = out_size / 2;                 // 1,048,576 threads
    int block = 256;
    int grid = (n_pairs + block - 1) / block;   // 4096

    maxpool4d_kernel<<<grid, block, 0, stream>>>(x4, out2);
}

// Round 2
// 25.238 us; speedup vs baseline: 1.0144x; 1.0144x over previous
//
#include <hip/hip_runtime.h>

// Fused 4D max pool, K=2 S=2 P=0 over (T,D,H,W) of [B=2,C=16,T=32,D=32,H=32,W=32] f32.
// Output [2,16,16,16,16,16] f32.
//
// Round 2: 4 outputs along W per thread. 16 independent float4 loads (2 per
// input row x 8 corner rows), two 8-way max trees, one float4 store.
// Reads input exactly once; fully-coalesced 16B stores; 2x the loads in
// flight per thread vs round 1.

#define IT   32
#define ID   32
#define IH   32          // input rows of 8 float4 (32 floats = 128 B)

__global__ __launch_bounds__(256) void maxpool4d_kernel(
    const float4* __restrict__ x4, float4* __restrict__ out4)
{
    int idx = blockIdx.x * blockDim.x + threadIdx.x;
    // idx = ((((bc*16 + ot)*16 + od)*16 + oh)*4 + owq)
    int owq = idx & 3;
    int oh  = (idx >> 2)  & 15;
    int od  = (idx >> 6)  & 15;
    int ot  = (idx >> 10) & 15;
    int bc  = idx >> 14;

    int t0 = ot << 1, d0 = od << 1, h0 = oh << 1;

    // input row index (rows of 8 float4): ((bc*IT + t)*ID + d)*IH + h
    int base = ((bc * IT + t0) * ID + d0) * IH + h0;

    float4 acc0, acc1;   // even / odd float4 of each row (w 0..3 / 4..7 of the 8-slot)
    bool first = true;
    #pragma unroll
    for (int tt = 0; tt < 2; ++tt) {
        #pragma unroll
        for (int dd = 0; dd < 2; ++dd) {
            #pragma unroll
            for (int hh = 0; hh < 2; ++hh) {
                int row = base + ((tt * ID + dd) * IH + hh);
                const float4* p = &x4[row * 8 + owq * 2];
                float4 v0 = p[0];
                float4 v1 = p[1];
                if (first) {
                    acc0 = v0; acc1 = v1; first = false;
                } else {
                    acc0.x = fmaxf(acc0.x, v0.x);
                    acc0.y = fmaxf(acc0.y, v0.y);
                    acc0.z = fmaxf(acc0.z, v0.z);
                    acc0.w = fmaxf(acc0.w, v0.w);
                    acc1.x = fmaxf(acc1.x, v1.x);
                    acc1.y = fmaxf(acc1.y, v1.y);
                    acc1.z = fmaxf(acc1.z, v1.z);
                    acc1.w = fmaxf(acc1.w, v1.w);
                }
            }
        }
    }

    float4 r;
    r.x = fmaxf(acc0.x, acc0.y);
    r.y = fmaxf(acc0.z, acc0.w);
    r.z = fmaxf(acc1.x, acc1.y);
    r.w = fmaxf(acc1.z, acc1.w);
    out4[idx] = r;
}

extern "C" void kernel_launch(void* const* d_in, const int* in_sizes, int n_in,
                              void* d_out, int out_size, void* d_ws, size_t ws_size,
                              hipStream_t stream)
{
    const float4* x4 = (const float4*)d_in[0];
    float4* out4 = (float4*)d_out;

    int n_threads = out_size / 4;               // 524,288
    int block = 256;
    int grid = (n_threads + block - 1) / block; // 2048

    maxpool4d_kernel<<<grid, block, 0, stream>>>(x4, out4);
}